// Round 9
// baseline (896.718 us; speedup 1.0000x reference)
//
#include <hip/hip_runtime.h>

// ---------------------------------------------------------------------------
// AttentionStack: 6-layer transformer, B=2, SEQ=1024, E=576, H=16, DK=36.
// dtype auto-detected (f32 vs bf16); bf16 MFMA GEMMs (LDS-staged, split-K,
// 128x64 / 128x128 tiles) + fp32 residual. Flash attention, XCD-swizzled.
// ---------------------------------------------------------------------------

#define E_    576
#define SEQ_  1024
#define B_    2
#define NH_   16
#define DK_   36
#define DKP_  64
#define NL_   6
#define FF_   2304
#define ROWS_ 2048

typedef unsigned short u16;
typedef unsigned int u32;
typedef float f32x4 __attribute__((ext_vector_type(4)));
typedef __bf16 bf16x8 __attribute__((ext_vector_type(8)));

#define MFMA16(a, b, c) __builtin_amdgcn_mfma_f32_16x16x32_bf16((a), (b), (c), 0, 0, 0)

__device__ __forceinline__ float bf2f(u16 u) {
    return __uint_as_float(((unsigned)u) << 16);
}
__device__ __forceinline__ u16 f2bf(float f) {
    unsigned u = __float_as_uint(f);
    u += 0x7fffu + ((u >> 16) & 1u);   // round-to-nearest-even
    return (u16)(u >> 16);
}
__device__ __forceinline__ float load_in(const void* p, size_t i, int isf32) {
    return isf32 ? ((const float*)p)[i] : bf2f(((const u16*)p)[i]);
}
__device__ __forceinline__ bf16x8 ldg8(const u16* p) {
    uint4 u = *(const uint4*)p;
    bf16x8 r;
    __builtin_memcpy(&r, &u, 16);
    return r;
}
__device__ __forceinline__ void gload_lds16(const u16* g, u16* l) {
    __builtin_amdgcn_global_load_lds(
        (const __attribute__((address_space(1))) unsigned int*)g,
        (__attribute__((address_space(3))) unsigned int*)l, 16, 0, 0);
}

// ---------------------------------------------------------------------------
__global__ void detect_kernel(const u16* __restrict__ x, int* __restrict__ flag)
{
    __shared__ float red[4];
    int lane = threadIdx.x & 63, wave = threadIdx.x >> 6;
    float mx = 0.f;
    for (int i = threadIdx.x; i < 4096; i += 256) {
        float v = fabsf(bf2f(x[i]));
        if (v < 3e38f) mx = fmaxf(mx, v);
    }
    for (int off = 1; off < 64; off <<= 1) mx = fmaxf(mx, __shfl_xor(mx, off));
    if (lane == 0) red[wave] = mx;
    __syncthreads();
    if (threadIdx.x == 0) {
        float m = fmaxf(fmaxf(red[0], red[1]), fmaxf(red[2], red[3]));
        *flag = (m > 1e6f) ? 1 : 0;
    }
}

// ---------------------------------------------------------------------------
// Weight repack v4: float4 vector loads (ILP; R7's VGPR=8 serialization fix)
// + v2's PROVEN conflict-free u16 [64][65] LDS (odd stride mixes bank parity;
// R8's u32[64][33] had 746K conflicts: 66p+s all-even -> 4-way).
// grid (972, 1, 6), block 256.
// ---------------------------------------------------------------------------
__global__ __launch_bounds__(256) void repack_kernel(
    const void* __restrict__ wq, const void* __restrict__ wk,
    const void* __restrict__ wv, const void* __restrict__ wo,
    const void* __restrict__ w1, const void* __restrict__ w2,
    u16* __restrict__ wT, const int* __restrict__ flagp)
{
    __shared__ u16 tile[64 * 65];
    int isf32 = *flagp;
    int idx = blockIdx.x, l = blockIdx.z;
    const void* src;
    u16* dst;
    size_t sbase;
    int R, C, cx, ry;
    if (idx < 324) {                        // wq/wk/wv/wo: 576x576, 81 tiles ea
        int t4 = idx / 81, rem = idx - t4 * 81;
        ry = rem / 9; cx = rem % 9; R = 576; C = 576;
        src = (t4 == 0) ? wq : (t4 == 1) ? wk : (t4 == 2) ? wv : wo;
        sbase = (size_t)l * 331776;
        dst = wT + (size_t)l * 3981312 + t4 * 331776;
    } else if (idx < 648) {                 // w1: 576x2304 -> 2304x576
        int rem = idx - 324;
        ry = rem / 36; cx = rem % 36; R = 576; C = 2304;
        src = w1; sbase = (size_t)l * 1327104;
        dst = wT + (size_t)l * 3981312 + 1327104;
    } else {                                // w2: 2304x576 -> 576x2304
        int rem = idx - 648;
        ry = rem / 9; cx = rem % 9; R = 2304; C = 576;
        src = w2; sbase = (size_t)l * 1327104;
        dst = wT + (size_t)l * 3981312 + 2654208;
    }
    int r0 = ry * 64, c0 = cx * 64;
    int t = threadIdx.x;
    int chunk = t & 15, row = t >> 4;       // 4 f32 (or 4 u16) per chunk
    if (isf32) {
        f32x4 v[4];
        #pragma unroll
        for (int i = 0; i < 4; i++) {
            int rr = row + i * 16;
            v[i] = *(const f32x4*)((const float*)src +
                    (sbase + (size_t)(r0 + rr) * C + c0 + chunk * 4));
        }
        #pragma unroll
        for (int i = 0; i < 4; i++) {
            int rr = row + i * 16;
            #pragma unroll
            for (int j = 0; j < 4; j++)
                tile[rr * 65 + chunk * 4 + j] = f2bf(v[i][j]);
        }
    } else {
        uint2 v[4];
        #pragma unroll
        for (int i = 0; i < 4; i++) {
            int rr = row + i * 16;
            v[i] = *(const uint2*)((const u16*)src +
                    (sbase + (size_t)(r0 + rr) * C + c0 + chunk * 4));
        }
        #pragma unroll
        for (int i = 0; i < 4; i++) {
            int rr = row + i * 16;
            tile[rr * 65 + chunk * 4 + 0] = (u16)(v[i].x & 0xffffu);
            tile[rr * 65 + chunk * 4 + 1] = (u16)(v[i].x >> 16);
            tile[rr * 65 + chunk * 4 + 2] = (u16)(v[i].y & 0xffffu);
            tile[rr * 65 + chunk * 4 + 3] = (u16)(v[i].y >> 16);
        }
    }
    __syncthreads();
    int p = t & 31, nl = t >> 5;
    #pragma unroll
    for (int i = 0; i < 8; i++) {
        int nn = nl + i * 8;
        u32 v = (u32)tile[(2 * p) * 65 + nn] | ((u32)tile[(2 * p + 1) * 65 + nn] << 16);
        u32* d32 = (u32*)(dst + (size_t)(c0 + nn) * R + r0);
        d32[p] = v;
    }
}

// ---------------------------------------------------------------------------
__global__ void embed_kernel(
    const void* __restrict__ x, const void* __restrict__ sos,
    const void* __restrict__ pe0, const void* __restrict__ pe1,
    const void* __restrict__ pe2, float* __restrict__ h,
    const int* __restrict__ flagp)
{
    int isf32 = *flagp;
    int row = blockIdx.x;
    int e = threadIdx.x;
    int s = row & 1023;
    float v = (s == 0) ? load_in(sos, e, isf32)
                       : load_in(x, (size_t)(row - 1) * E_ + e, isf32);
    int t = s >> 8, hh = (s >> 4) & 15, ww = s & 15;
    float p = (e < 192) ? load_in(pe0, t * 192 + e, isf32)
            : (e < 384) ? load_in(pe1, hh * 192 + e - 192, isf32)
                        : load_in(pe2, ww * 192 + e - 384, isf32);
    h[(size_t)row * E_ + e] = v + p;
}

// ---------------------------------------------------------------------------
__global__ __launch_bounds__(256) void ln_kernel(
    const float* __restrict__ h, u16* __restrict__ y,
    const void* __restrict__ sc, const void* __restrict__ bi,
    int off0, const int* __restrict__ flagp)
{
    int isf32 = *flagp;
    int lane = threadIdx.x & 63, wave = threadIdx.x >> 6;
    int row = blockIdx.x * 4 + wave;
    const float* hr = h + (size_t)row * E_;
    float v[9], s = 0.f, sq = 0.f;
    for (int j = 0; j < 9; j++) {
        v[j] = hr[lane + j * 64];
        s += v[j];
        sq += v[j] * v[j];
    }
    for (int off = 1; off < 64; off <<= 1) {
        s += __shfl_xor(s, off);
        sq += __shfl_xor(sq, off);
    }
    float mean = s * (1.0f / E_);
    float var = sq * (1.0f / E_) - mean * mean;
    float r = rsqrtf(var + 1e-5f);
    for (int j = 0; j < 9; j++) {
        int e = lane + j * 64;
        float sce = load_in(sc, off0 + e, isf32);
        float bie = load_in(bi, off0 + e, isf32);
        y[(size_t)row * E_ + e] = f2bf((v[j] - mean) * r * sce + bie);
    }
}

// ---------------------------------------------------------------------------
// GEMM v3: block tile 128(M) x BN(N), 4 waves 2x2. Wave tile 64 x BN/2:
// BN=64 -> 8 MFMA per 6 ds_read_b128 per ks; BN=128 -> 16 per 8.
// LDS-staged via global_load_lds 16B, XOR chunk swizzle, BK=64, split-K.
// MODE 0: QKV  MODE 1: O-proj(+res, splitK)  MODE 2: MLP1+gelu2  MODE 3: MLP2
// ---------------------------------------------------------------------------
template <int MODE, int SPLITK, int BN>
__global__ __launch_bounds__(256) void gemm_kernel(
    const u16* __restrict__ A, const u16* __restrict__ BtBase, int K,
    const void* __restrict__ bias, int boff, float* __restrict__ hbuf,
    u16* __restrict__ out, u16* __restrict__ qb, u16* __restrict__ kb,
    u16* __restrict__ vtb, const int* __restrict__ flagp)
{
    const int NI = BN / 32;          // n-frags per wave
    const int NRB = BN / 32;         // B staging rounds
    __shared__ u16 lA[8192];         // 128 x 64
    __shared__ u16 lB[BN * 64];
    int t = threadIdx.x;
    int lane = t & 63, wave = t >> 6;
    int lw = lane & 15, lq = lane >> 4;
    int wx = wave >> 1, wy = wave & 1;
    int m0 = blockIdx.x * 128, n0 = blockIdx.y * BN;
    int z = blockIdx.z / SPLITK, kz = blockIdx.z % SPLITK;
    int Ks = K / SPLITK, kbase = kz * Ks;

    const u16* Bt = BtBase + (MODE == 0 ? (size_t)z * 331776 : 0);
    int rowS = t >> 3;
    int gc = (t & 7) ^ (rowS & 7);
    const u16* gA = A + (size_t)(m0 + rowS) * K + kbase + gc * 8;
    const u16* gB = Bt + (size_t)(n0 + rowS) * K + kbase + gc * 8;
    size_t rstep = (size_t)32 * K;

    f32x4 acc[4][NI];
    for (int mi = 0; mi < 4; mi++)
        for (int ni = 0; ni < NI; ni++)
            for (int r = 0; r < 4; r++) acc[mi][ni][r] = 0.f;

    for (int kc = 0; kc < Ks; kc += 64) {
        #pragma unroll
        for (int ra = 0; ra < 4; ra++)
            gload_lds16(gA + ra * rstep + kc, &lA[ra * 2048 + t * 8]);
        #pragma unroll
        for (int rb = 0; rb < NRB; rb++)
            gload_lds16(gB + rb * rstep + kc, &lB[rb * 2048 + t * 8]);
        __syncthreads();
        #pragma unroll
        for (int ks = 0; ks < 2; ks++) {
            int csw = ((ks * 4 + lq) ^ (lw & 7)) * 8;
            bf16x8 bf[NI];
            #pragma unroll
            for (int ni = 0; ni < NI; ni++)
                bf[ni] = ldg8(&lB[(wy * (BN / 2) + ni * 16 + lw) * 64 + csw]);
            #pragma unroll
            for (int mi = 0; mi < 4; mi++) {
                bf16x8 af = ldg8(&lA[(wx * 64 + mi * 16 + lw) * 64 + csw]);
                #pragma unroll
                for (int ni = 0; ni < NI; ni++)
                    acc[mi][ni] = MFMA16(af, bf[ni], acc[mi][ni]);
            }
        }
        __syncthreads();
    }

    int isf32 = (MODE != 0) ? *flagp : 0;
    #pragma unroll
    for (int ni = 0; ni < NI; ni++) {
        int n = n0 + wy * (BN / 2) + ni * 16 + lw;
        float bn = 0.f;
        if (MODE == 2 || ((MODE == 1 || MODE == 3) && kz == 0))
            bn = load_in(bias, boff + n, isf32);
        #pragma unroll
        for (int mi = 0; mi < 4; mi++) {
            #pragma unroll
            for (int r = 0; r < 4; r++) {
                int m = m0 + wx * 64 + mi * 16 + lq * 4 + r;
                float v = acc[mi][ni][r];
                if (MODE == 0) {
                    int b = m >> 10, s = m & 1023;
                    int head = n / 36, d = n - head * 36;
                    size_t bh = (size_t)(b * NH_ + head);
                    if (z == 0)
                        qb[(bh * SEQ_ + s) * DKP_ + d] = f2bf(v * (1.0f / 6.0f));
                    else if (z == 1)
                        kb[(bh * SEQ_ + s) * DKP_ + d] = f2bf(v);
                    else
                        vtb[(bh * DKP_ + d) * SEQ_ + s] = f2bf(v);
                } else if (MODE == 2) {
                    float tt = v + bn;
                    out[(size_t)m * FF_ + n] = f2bf(tt / (1.0f + __expf(-1.702f * tt)));
                } else {
                    atomicAdd(&hbuf[(size_t)m * E_ + n], v + bn);
                }
            }
        }
    }
}

// ---------------------------------------------------------------------------
// Flash attention v4: as v3 (flat grid 2048 XCD-swizzled, 16 q-rows/block,
// waves split kv chunks, flash-decode merge) but per-wave P-buffer and
// O-partial buffer UNION one LDS region (each wave reuses only its own
// region after its last P read) -> LDS 22.3 -> ~14 KB -> 4 blocks/CU.
// ---------------------------------------------------------------------------
__global__ __launch_bounds__(256) void attn_kernel(
    const u16* __restrict__ qb, const u16* __restrict__ kb,
    const u16* __restrict__ vtb, u16* __restrict__ ob)
{
    __shared__ __align__(16) char usmem[4][3392];  // per-wave union:
    // during loop: u32 plds[16][33] (2112B); after loop: f32 so[16][52] (3328B)
    __shared__ float sm[4][16], sl[4][16];
    int lane = threadIdx.x & 63, wave = threadIdx.x >> 6;
    int lw = lane & 15, lq = lane >> 4;
    int L = blockIdx.x;
    int bh = L & 31;                      // XCD affinity
    int qt = 63 - (L >> 5);
    int head = bh & 15, b = bh >> 4;
    int q0 = qt * 16;
    u32 (*pl)[33] = (u32(*)[33])usmem[wave];

    const u16* qbase = qb + ((size_t)bh * SEQ_ + q0) * DKP_;
    bf16x8 qf0 = ldg8(qbase + lw * DKP_ + lq * 8);
    bf16x8 qf1 = ldg8(qbase + lw * DKP_ + 32 + lq * 8);

    int tq = q0 >> 8, hq = (q0 >> 4) & 15;
    float m_i[4], l_i[4], ew[4];
    f32x4 oacc[3];
    int qi[4];
    for (int r = 0; r < 4; r++) {
        m_i[r] = -1e30f;
        l_i[r] = 0.f;
        qi[r] = q0 + lq * 4 + r;
        ew[r] = __expf((float)abs(lw - (lq * 4 + r)) * (-1.0f / 33.0f));
    }
    for (int c = 0; c < 3; c++)
        for (int r = 0; r < 4; r++) oacc[c][r] = 0.f;

    int nch = (q0 + 79) >> 6;
    for (int c = wave; c < nch; c += 4) {
        int kv0 = c * 64;
        bool diag = (c == nch - 1);
        bf16x8 kf[4][2], vf[3][2];
        #pragma unroll
        for (int kvh = 0; kvh < 4; kvh++) {
            const u16* krow =
                kb + ((size_t)bh * SEQ_ + kv0 + kvh * 16 + lw) * DKP_ + lq * 8;
            kf[kvh][0] = ldg8(krow);
            kf[kvh][1] = ldg8(krow + 32);
        }
        #pragma unroll
        for (int c2 = 0; c2 < 3; c2++) {
            const u16* vrow =
                vtb + ((size_t)bh * DKP_ + c2 * 16 + lw) * SEQ_ + kv0 + lq * 8;
            vf[c2][0] = ldg8(vrow);
            vf[c2][1] = ldg8(vrow + 32);
        }
        f32x4 st[4];
        #pragma unroll
        for (int kvh = 0; kvh < 4; kvh++) {
            f32x4 tt;
            for (int r = 0; r < 4; r++) tt[r] = 0.f;
            tt = MFMA16(qf0, kf[kvh][0], tt);
            tt = MFMA16(qf1, kf[kvh][1], tt);
            st[kvh] = tt;
        }
        float sA[4];
        #pragma unroll
        for (int kvh = 0; kvh < 4; kvh++) {
            int kk = kv0 + kvh * 16;
            int d = abs((kk >> 8) - tq) + abs(((kk >> 4) & 15) - hq);
            sA[kvh] = __expf((float)d * (-1.0f / 33.0f));
        }
        #pragma unroll
        for (int r = 0; r < 4; r++) {
            float v0 = st[0][r] * (sA[0] * ew[r]);
            float v1 = st[1][r] * (sA[1] * ew[r]);
            float v2 = st[2][r] * (sA[2] * ew[r]);
            float v3 = st[3][r] * (sA[3] * ew[r]);
            if (diag) {
                if (kv0 + 0 * 16 + lw > qi[r]) v0 = -1e30f;
                if (kv0 + 1 * 16 + lw > qi[r]) v1 = -1e30f;
                if (kv0 + 2 * 16 + lw > qi[r]) v2 = -1e30f;
                if (kv0 + 3 * 16 + lw > qi[r]) v3 = -1e30f;
            }
            float m2 = fmaxf(fmaxf(v0, v1), fmaxf(v2, v3));
            for (int off = 1; off < 16; off <<= 1)
                m2 = fmaxf(m2, __shfl_xor(m2, off));
            float mn = fmaxf(m_i[r], m2);
            float alpha = __expf(m_i[r] - mn);
            m_i[r] = mn;
            float p0 = __expf(v0 - mn), p1 = __expf(v1 - mn);
            float p2 = __expf(v2 - mn), p3 = __expf(v3 - mn);
            u32 a01 = (u32)f2bf(p0) | ((u32)f2bf(p1) << 16);
            u32 a23 = (u32)f2bf(p2) | ((u32)f2bf(p3) << 16);
            u32 b01 = (u32)__shfl_xor((int)a01, 1);
            u32 b23 = (u32)__shfl_xor((int)a23, 1);
            if (!(lw & 1)) {
                int ro = lq * 4 + r, w2 = lw >> 1;
                pl[ro][w2 + 0]  = ((b01 & 0xffffu) << 16) | (a01 & 0xffffu);
                pl[ro][w2 + 8]  = (b01 & 0xffff0000u) | (a01 >> 16);
                pl[ro][w2 + 16] = ((b23 & 0xffffu) << 16) | (a23 & 0xffffu);
                pl[ro][w2 + 24] = (b23 & 0xffff0000u) | (a23 >> 16);
            }
            float rs = (p0 + p1) + (p2 + p3);
            for (int off = 1; off < 16; off <<= 1)
                rs += __shfl_xor(rs, off);
            l_i[r] = l_i[r] * alpha + rs;
            for (int c2 = 0; c2 < 3; c2++) oacc[c2][r] *= alpha;
        }
        __asm__ volatile("s_waitcnt lgkmcnt(0)" ::: "memory");
        uint4 u0 = *(const uint4*)&pl[lw][lq * 4];
        uint4 u1 = *(const uint4*)&pl[lw][16 + lq * 4];
        bf16x8 pf0, pf1;
        __builtin_memcpy(&pf0, &u0, 16);
        __builtin_memcpy(&pf1, &u1, 16);
        #pragma unroll
        for (int c2 = 0; c2 < 3; c2++) {
            oacc[c2] = MFMA16(pf0, vf[c2][0], oacc[c2]);
            oacc[c2] = MFMA16(pf1, vf[c2][1], oacc[c2]);
        }
    }
    // publish per-wave state into the union region (own wave only), merge
    __asm__ volatile("s_waitcnt lgkmcnt(0)" ::: "memory");
    float (*sow)[52] = (float(*)[52])usmem[wave];
    #pragma unroll
    for (int r = 0; r < 4; r++) {
        int ro = lq * 4 + r;
        if (lw == 0) { sm[wave][ro] = m_i[r]; sl[wave][ro] = l_i[r]; }
        for (int c2 = 0; c2 < 3; c2++)
            sow[ro][c2 * 16 + lw] = oacc[c2][r];
    }
    __syncthreads();
    for (int i = threadIdx.x; i < 16 * DK_; i += 256) {
        int row = i / DK_, col = i - row * DK_;
        float M = fmaxf(fmaxf(sm[0][row], sm[1][row]),
                        fmaxf(sm[2][row], sm[3][row]));
        float Lm = 0.f, O = 0.f;
        #pragma unroll
        for (int w = 0; w < 4; w++) {
            float f = __expf(sm[w][row] - M);
            Lm += f * sl[w][row];
            O += f * ((const float(*)[52])usmem[w])[row][col];
        }
        ob[((size_t)b * SEQ_ + q0 + row) * E_ + head * DK_ + col] = f2bf(O / Lm);
    }
}

// ---------------------------------------------------------------------------
__global__ void out_kernel(const float* __restrict__ h, void* __restrict__ out,
                           const int* __restrict__ flagp)
{
    int isf32 = *flagp;
    int i = blockIdx.x * blockDim.x + threadIdx.x;
    if (isf32) ((float*)out)[i] = h[i];
    else       ((u16*)out)[i] = f2bf(h[i]);
}

// ---------------------------------------------------------------------------
extern "C" void kernel_launch(void* const* d_in, const int* in_sizes, int n_in,
                              void* d_out, int out_size, void* d_ws,
                              size_t ws_size, hipStream_t stream)
{
    const void* x    = d_in[0];
    const void* sos  = d_in[1];
    const void* pe0  = d_in[2];
    const void* pe1  = d_in[3];
    const void* pe2  = d_in[4];
    const void* ln1s = d_in[5];
    const void* ln1b = d_in[6];
    const void* wq   = d_in[7];
    const void* wk   = d_in[8];
    const void* wv   = d_in[9];
    const void* wo   = d_in[10];
    const void* bo   = d_in[11];
    const void* ln2s = d_in[12];
    const void* ln2b = d_in[13];
    const void* w1   = d_in[14];
    const void* b1   = d_in[15];
    const void* w2   = d_in[16];
    const void* b2   = d_in[17];

    char* ws = (char*)d_ws;
    u16*   qbuf  = (u16*)(ws + 0);          //  4 MB  [B,H,SEQ,64] bf16
    u16*   kbuf  = (u16*)(ws + 4194304);    //  4 MB
    u16*   vtbuf = (u16*)(ws + 8388608);    //  4 MB  [B,H,64,SEQ] bf16
    float* h     = (float*)(ws + 12582912); //  4.7 MB fp32 residual stream
    u16*   y     = (u16*)(ws + 17301504);   //  2.36 MB LN output
    u16*   o     = (u16*)(ws + 19660800);   //  2.36 MB attention output
    u16*   y1    = (u16*)(ws + 22020096);   //  9.4 MB MLP hidden
    u16*   wT    = (u16*)(ws + 31457280);   // 47.8 MB repacked weights
    int*   flag  = (int*)(ws + 79233024);   // dtype flag

    hipMemsetAsync(ws, 0, 12582912, stream);
    detect_kernel<<<1, 256, 0, stream>>>((const u16*)x, flag);
    repack_kernel<<<dim3(972, 1, 6), 256, 0, stream>>>(
        wq, wk, wv, wo, w1, w2, wT, flag);
    embed_kernel<<<ROWS_, E_, 0, stream>>>(x, sos, pe0, pe1, pe2, h, flag);

    for (int l = 0; l < NL_; l++) {
        u16* wTl = wT + (size_t)l * 3981312;
        ln_kernel<<<512, 256, 0, stream>>>(h, y, ln1s, ln1b, l * E_, flag);
        gemm_kernel<0, 1, 64><<<dim3(16, 9, 3), 256, 0, stream>>>(
            y, wTl, E_, nullptr, 0, nullptr, nullptr, qbuf, kbuf, vtbuf, flag);
        attn_kernel<<<dim3(2048), 256, 0, stream>>>(qbuf, kbuf, vtbuf, o);
        gemm_kernel<1, 3, 64><<<dim3(16, 9, 3), 256, 0, stream>>>(
            o, wTl + 995328, E_, bo, l * E_, h, nullptr, nullptr, nullptr, nullptr, flag);
        ln_kernel<<<512, 256, 0, stream>>>(h, y, ln2s, ln2b, l * E_, flag);
        gemm_kernel<2, 1, 128><<<dim3(16, 18, 1), 256, 0, stream>>>(
            y, wTl + 1327104, E_, b1, l * FF_, nullptr, y1, nullptr, nullptr, nullptr, flag);
        gemm_kernel<3, 4, 64><<<dim3(16, 9, 4), 256, 0, stream>>>(
            y1, wTl + 2654208, FF_, b2, l * E_, h, nullptr, nullptr, nullptr, nullptr, flag);
    }
    out_kernel<<<4608, 256, 0, stream>>>(h, d_out, flag);
}